// Round 7
// baseline (139.395 us; speedup 1.0000x reference)
//
#include <hip/hip_runtime.h>
#include <math.h>

#define DIM 128
#define NODE_CHUNK 64
#define QPB_MAX 64      // max edge-quads per block (=> <=256 edges/block in LDS)
#define GRID_P 2048

// native clang vector types — required by __builtin_nontemporal_load / packed ops
typedef float vfloat4 __attribute__((ext_vector_type(4)));
typedef int   vint4   __attribute__((ext_vector_type(4)));

__device__ __forceinline__ float reduce16(float v) {
    v += __shfl_xor(v, 1);
    v += __shfl_xor(v, 2);
    v += __shfl_xor(v, 4);
    v += __shfl_xor(v, 8);
    return v;
}

__device__ __forceinline__ float dp4(vfloat4 a, vfloat4 b) {
    return a.x * b.x + a.y * b.y + a.z * b.z + a.w * b.w;
}

__device__ __forceinline__ vfloat4 ntload(const float* p) {
    return __builtin_nontemporal_load(reinterpret_cast<const vfloat4*>(p));
}

__device__ __forceinline__ float sigmoidf(float x) {
    return 1.0f / (1.0f + __expf(-x));
}

// ---------------------------------------------------------------------------
// Persistent fused kernel.
//  Phase 0: cooperatively drain node-projection queue (pk/pi into d_ws),
//           publish completion via device-scope release add.  Deadlock-free:
//           only blocks that grabbed a chunk are awaited, and they're running.
//  Phase 1: stream this block's contiguous edge slice; s = e·We kept in LDS;
//           src/dst slice prefetched into LDS (overlaps the stream).
//  Phase 2: acquire-spin until all node chunks done (normally already true).
//  Phase 3: out = sigmoid(s + pk[src] + pi[dst] + b), coalesced stores.
// ---------------------------------------------------------------------------
__global__ __launch_bounds__(256) void fused_persistent(
        const float* __restrict__ h,
        const float* __restrict__ e,
        const int* __restrict__ src,
        const int* __restrict__ dst,
        const float* __restrict__ W,
        const float* __restrict__ b,
        int* __restrict__ ctrs,      // [0]=node queue, [1]=done count (pre-zeroed)
        float* __restrict__ pk,
        float* __restrict__ pi,
        float* __restrict__ out,
        int n_nodes, int n_edges, int nchunks, int qpb) {
    __shared__ float s_lds[QPB_MAX * 4];
    __shared__ int   lsrc[QPB_MAX * 4];
    __shared__ int   ldst[QPB_MAX * 4];
    __shared__ int   c_bcast;

    const int tid = threadIdx.x;
    const int l   = tid & 15;
    const int g   = tid >> 4;    // group 0..15, one edge/node quad per group

    // ---- Phase 0: node projections via dynamic work queue ----
    {
        const vfloat4 wk0 = *reinterpret_cast<const vfloat4*>(W + 4 * l);
        const vfloat4 wk1 = *reinterpret_cast<const vfloat4*>(W + 64 + 4 * l);
        const vfloat4 wi0 = *reinterpret_cast<const vfloat4*>(W + DIM + 4 * l);
        const vfloat4 wi1 = *reinterpret_cast<const vfloat4*>(W + DIM + 64 + 4 * l);

        int my_chunks = 0;
        for (;;) {
            if (tid == 0) c_bcast = atomicAdd(&ctrs[0], 1);
            __syncthreads();
            const int c = c_bcast;
            __syncthreads();   // allows c_bcast rewrite; drains prev chunk's stores
            if (c >= nchunks) break;
            ++my_chunks;

            const int nb = c * NODE_CHUNK + 4 * g;
            if (nb < n_nodes) {
                const bool full = (nb + 4 <= n_nodes);
                vfloat4 a0[4], a1[4];
#pragma unroll
                for (int j = 0; j < 4; ++j) {
                    int row = nb + j;
                    if (row > n_nodes - 1) row = n_nodes - 1;
                    const float* hp = h + (size_t)row * DIM;
                    a0[j] = ntload(hp + 4 * l);
                    a1[j] = ntload(hp + 64 + 4 * l);
                }
                float sk[4], si[4];
#pragma unroll
                for (int j = 0; j < 4; ++j) {
                    sk[j] = reduce16(dp4(a0[j], wk0) + dp4(a1[j], wk1));
                    si[j] = reduce16(dp4(a0[j], wi0) + dp4(a1[j], wi1));
                }
                if (l == 0) {
                    if (full) {
                        vfloat4 vk; vk.x = sk[0]; vk.y = sk[1]; vk.z = sk[2]; vk.w = sk[3];
                        vfloat4 vi; vi.x = si[0]; vi.y = si[1]; vi.z = si[2]; vi.w = si[3];
                        *reinterpret_cast<vfloat4*>(pk + nb) = vk;
                        *reinterpret_cast<vfloat4*>(pi + nb) = vi;
                    } else {
                        for (int j = 0; j < 4 && nb + j < n_nodes; ++j) {
                            pk[nb + j] = sk[j];
                            pi[nb + j] = si[j];
                        }
                    }
                }
            }
        }
        __syncthreads();   // every wave drains its pk/pi stores (vmcnt 0) before publish
        if (tid == 0 && my_chunks > 0) {
            // agent-scope release: L2 writeback so pk/pi are visible cross-XCD
            __hip_atomic_fetch_add(&ctrs[1], my_chunks,
                                   __ATOMIC_RELEASE, __HIP_MEMORY_SCOPE_AGENT);
        }
    }

    // ---- Phase 1: stream this block's edge slice; results to LDS ----
    const int NQ = (n_edges + 3) >> 2;
    const int q0 = (int)blockIdx.x * qpb;
    const int q1 = min(q0 + qpb, NQ);
    const int e0 = q0 * 4;
    const int e_end = min(q1 * 4, n_edges);
    const int edges_blk = e_end - e0;   // may be <= 0 for trailing blocks

    // prefetch indices into LDS (coalesced; overlaps with the stream)
    for (int t = tid; t < edges_blk; t += 256) {
        lsrc[t] = src[e0 + t];
        ldst[t] = dst[e0 + t];
    }

    {
        const vfloat4 we0 = *reinterpret_cast<const vfloat4*>(W + 2 * DIM + 4 * l);
        const vfloat4 we1 = *reinterpret_cast<const vfloat4*>(W + 2 * DIM + 64 + 4 * l);

        for (int qq = q0 + g; qq < q1; qq += 16) {
            const int base = qq * 4;
            vfloat4 a0[4], a1[4];
#pragma unroll
            for (int j = 0; j < 4; ++j) {
                int row = base + j;
                if (row > n_edges - 1) row = n_edges - 1;   // clamp (tail safety)
                const float* ep = e + (size_t)row * DIM;
                a0[j] = ntload(ep + 4 * l);
                a1[j] = ntload(ep + 64 + 4 * l);
            }
            float s[4];
#pragma unroll
            for (int j = 0; j < 4; ++j)
                s[j] = reduce16(dp4(a0[j], we0) + dp4(a1[j], we1));
            if (l == 0) {
                vfloat4 o; o.x = s[0]; o.y = s[1]; o.z = s[2]; o.w = s[3];
                *reinterpret_cast<vfloat4*>(&s_lds[(qq - q0) * 4]) = o;
            }
        }
    }

    // ---- Phase 2: wait for all node chunks (expected: already complete) ----
    if (tid == 0) {
        long spins = 0;
        while (__hip_atomic_load(&ctrs[1], __ATOMIC_ACQUIRE,
                                 __HIP_MEMORY_SCOPE_AGENT) < nchunks) {
            __builtin_amdgcn_s_sleep(8);
            if (++spins > (1L << 28)) break;   // safety valve vs. hang
        }
    }
    __syncthreads();   // also orders s_lds writes before cross-group reads

    // ---- Phase 3: finish — gather pk/pi, sigmoid, coalesced store ----
    if (tid < edges_blk) {
        const float b0  = b[0];
        const float sv  = s_lds[tid];
        const float pkv = pk[lsrc[tid]];
        const float piv = pi[ldst[tid]];
        out[e0 + tid] = sigmoidf(sv + pkv + piv + b0);
    }
}

// ---------------------------------------------------------------------------
// Fallback path (R5): two kernels, proven 50.8us.
// ---------------------------------------------------------------------------
__global__ __launch_bounds__(256) void node_proj_kernel(
        const float* __restrict__ h,
        const float* __restrict__ W,
        float* __restrict__ pk,
        float* __restrict__ pi,
        int n_nodes) {
    const int l = threadIdx.x & 15;
    const int group0 = (blockIdx.x * blockDim.x + threadIdx.x) >> 4;
    const int ngroups = (gridDim.x * blockDim.x) >> 4;

    const vfloat4 wk0 = *reinterpret_cast<const vfloat4*>(W + 4 * l);
    const vfloat4 wk1 = *reinterpret_cast<const vfloat4*>(W + 64 + 4 * l);
    const vfloat4 wi0 = *reinterpret_cast<const vfloat4*>(W + DIM + 4 * l);
    const vfloat4 wi1 = *reinterpret_cast<const vfloat4*>(W + DIM + 64 + 4 * l);

    for (int node = group0; node < n_nodes; node += ngroups) {
        const float* hp = h + (size_t)node * DIM;
        const vfloat4 a0 = ntload(hp + 4 * l);
        const vfloat4 a1 = ntload(hp + 64 + 4 * l);
        float sk = reduce16(dp4(a0, wk0) + dp4(a1, wk1));
        float si = reduce16(dp4(a0, wi0) + dp4(a1, wi1));
        if (l == 0) { pk[node] = sk; pi[node] = si; }
    }
}

__global__ __launch_bounds__(256) void edge_kernel(
        const float* __restrict__ e,
        const int* __restrict__ src,
        const int* __restrict__ dst,
        const float* __restrict__ W,
        const float* __restrict__ b,
        const float* __restrict__ pk,
        const float* __restrict__ pi,
        float* __restrict__ out,
        int n_edges) {
    const int l = threadIdx.x & 15;
    const int group0 = (blockIdx.x * blockDim.x + threadIdx.x) >> 4;
    const int ngroups = (gridDim.x * blockDim.x) >> 4;

    const vfloat4 we0 = *reinterpret_cast<const vfloat4*>(W + 2 * DIM + 4 * l);
    const vfloat4 we1 = *reinterpret_cast<const vfloat4*>(W + 2 * DIM + 64 + 4 * l);
    const float b0 = b[0];

    const int n_full = n_edges & ~3;

    for (int base = 4 * group0; base < n_full; base += 4 * ngroups) {
        const vint4 s4 = *reinterpret_cast<const vint4*>(src + base);
        const vint4 d4 = *reinterpret_cast<const vint4*>(dst + base);
        float pkv[4], piv[4];
        pkv[0] = pk[s4.x]; pkv[1] = pk[s4.y]; pkv[2] = pk[s4.z]; pkv[3] = pk[s4.w];
        piv[0] = pi[d4.x]; piv[1] = pi[d4.y]; piv[2] = pi[d4.z]; piv[3] = pi[d4.w];

        const float* ep = e + (size_t)base * DIM;
        vfloat4 a0[4], a1[4];
#pragma unroll
        for (int j = 0; j < 4; ++j) {
            a0[j] = ntload(ep + (size_t)j * DIM + 4 * l);
            a1[j] = ntload(ep + (size_t)j * DIM + 64 + 4 * l);
        }
        float s[4];
#pragma unroll
        for (int j = 0; j < 4; ++j)
            s[j] = reduce16(dp4(a0[j], we0) + dp4(a1[j], we1));

        if (l == 0) {
            vfloat4 o;
            o.x = sigmoidf(s[0] + pkv[0] + piv[0] + b0);
            o.y = sigmoidf(s[1] + pkv[1] + piv[1] + b0);
            o.z = sigmoidf(s[2] + pkv[2] + piv[2] + b0);
            o.w = sigmoidf(s[3] + pkv[3] + piv[3] + b0);
            *reinterpret_cast<vfloat4*>(out + base) = o;
        }
    }
    for (int edge = n_full + group0; edge < n_edges; edge += ngroups) {
        const float pkv = pk[src[edge]];
        const float piv = pi[dst[edge]];
        const float* ep = e + (size_t)edge * DIM;
        const vfloat4 a0 = ntload(ep + 4 * l);
        const vfloat4 a1 = ntload(ep + 64 + 4 * l);
        float s = reduce16(dp4(a0, we0) + dp4(a1, we1));
        if (l == 0) out[edge] = sigmoidf(s + pkv + piv + b0);
    }
}

// Last-resort fallback: fully fused, gathers h rows per edge.
__global__ void edge_fused_kernel(const float* __restrict__ h,
                                  const float* __restrict__ e,
                                  const int* __restrict__ src,
                                  const int* __restrict__ dst,
                                  const float* __restrict__ W,
                                  const float* __restrict__ b,
                                  float* __restrict__ out,
                                  int n_edges) {
    int tid  = blockIdx.x * blockDim.x + threadIdx.x;
    int edge = tid >> 5;
    int l    = tid & 31;
    if (edge >= n_edges) return;

    int s_idx = src[edge];
    int d_idx = dst[edge];

    const float4 hk = *reinterpret_cast<const float4*>(h + (size_t)s_idx * DIM + 4 * l);
    const float4 hi = *reinterpret_cast<const float4*>(h + (size_t)d_idx * DIM + 4 * l);
    const float4 ev = *reinterpret_cast<const float4*>(e + (size_t)edge * DIM + 4 * l);
    const float4 wk = *reinterpret_cast<const float4*>(W + 4 * l);
    const float4 wi = *reinterpret_cast<const float4*>(W + DIM + 4 * l);
    const float4 we = *reinterpret_cast<const float4*>(W + 2 * DIM + 4 * l);

    float s = hk.x * wk.x + hk.y * wk.y + hk.z * wk.z + hk.w * wk.w
            + hi.x * wi.x + hi.y * wi.y + hi.z * wi.z + hi.w * wi.w
            + ev.x * we.x + ev.y * we.y + ev.z * we.z + ev.w * we.w;
    s += __shfl_xor(s, 1);
    s += __shfl_xor(s, 2);
    s += __shfl_xor(s, 4);
    s += __shfl_xor(s, 8);
    s += __shfl_xor(s, 16);

    if (l == 0) {
        float logit = s + b[0];
        out[edge] = 1.0f / (1.0f + expf(-logit));
    }
}

extern "C" void kernel_launch(void* const* d_in, const int* in_sizes, int n_in,
                              void* d_out, int out_size, void* d_ws, size_t ws_size,
                              hipStream_t stream) {
    const float* h   = (const float*)d_in[0];
    const float* e   = (const float*)d_in[1];
    const int*   src = (const int*)d_in[2];
    const int*   dst = (const int*)d_in[3];
    const float* W   = (const float*)d_in[4];
    const float* b   = (const float*)d_in[5];
    float* out = (float*)d_out;

    const int n_nodes = in_sizes[0] / DIM;
    const int n_edges = in_sizes[2];

    const int n_nodes_pad = (n_nodes + 3) & ~3;
    const size_t ws_persist = 16 + (size_t)2 * n_nodes_pad * sizeof(float);
    const size_t ws_mid     = (size_t)2 * n_nodes_pad * sizeof(float);

    const int NQ  = (n_edges + 3) / 4;
    const int qpb = (NQ + GRID_P - 1) / GRID_P;

    if (ws_size >= ws_persist && qpb <= QPB_MAX) {
        int*   ctrs = (int*)d_ws;
        float* pk   = (float*)((char*)d_ws + 16);
        float* pi   = pk + n_nodes_pad;

        hipMemsetAsync(d_ws, 0, 16, stream);   // reset queue + done counters

        const int nchunks = (n_nodes + NODE_CHUNK - 1) / NODE_CHUNK;
        fused_persistent<<<GRID_P, 256, 0, stream>>>(
            h, e, src, dst, W, b, ctrs, pk, pi, out,
            n_nodes, n_edges, nchunks, qpb);
    } else if (ws_size >= ws_mid) {
        float* pk = (float*)d_ws;
        float* pi = pk + n_nodes_pad;

        {
            const int block = 256;
            long total = (long)n_nodes * 16;
            int grid = (int)((total + block - 1) / block);
            if (grid > 2048) grid = 2048;
            node_proj_kernel<<<grid, block, 0, stream>>>(h, W, pk, pi, n_nodes);
        }
        {
            const int block = 256;
            long total = ((long)n_edges + 3) / 4 * 16;
            int grid = (int)((total + block - 1) / block);
            if (grid > 2048) grid = 2048;
            edge_kernel<<<grid, block, 0, stream>>>(e, src, dst, W, b, pk, pi, out, n_edges);
        }
    } else {
        int total = n_edges * 32;
        int block = 256;
        int grid  = (total + block - 1) / block;
        edge_fused_kernel<<<grid, block, 0, stream>>>(h, e, src, dst, W, b, out, n_edges);
    }
}

// Round 8
// 50.889 us; speedup vs baseline: 2.7392x; 2.7392x over previous
//
#include <hip/hip_runtime.h>
#include <math.h>

#define DIM 128

// native clang vector types — required by __builtin_nontemporal_load / packed stores
typedef float vfloat4 __attribute__((ext_vector_type(4)));
typedef int   vint4   __attribute__((ext_vector_type(4)));

__device__ __forceinline__ float reduce16(float v) {
    // butterfly reduce within each 16-lane group of the wave64 (result in all lanes)
    v += __shfl_xor(v, 1);
    v += __shfl_xor(v, 2);
    v += __shfl_xor(v, 4);
    v += __shfl_xor(v, 8);
    return v;
}

__device__ __forceinline__ float dp4(vfloat4 a, vfloat4 b) {
    return a.x * b.x + a.y * b.y + a.z * b.z + a.w * b.w;
}

__device__ __forceinline__ vfloat4 ntload(const float* p) {
    return __builtin_nontemporal_load(reinterpret_cast<const vfloat4*>(p));
}

__device__ __forceinline__ float sigmoidf(float x) {
    return 1.0f / (1.0f + __expf(-x));
}

// Kernel 1: per-node projections pk[n] = h[n]·W[0:128], pi[n] = h[n]·W[128:256]
// 16 lanes/node; lane l covers floats [4l,4l+4) and [64+4l,64+4l+4). 4 nodes/iter.
__global__ __launch_bounds__(256) void node_proj_kernel(
        const float* __restrict__ h,
        const float* __restrict__ W,
        float* __restrict__ pk,
        float* __restrict__ pi,
        int n_nodes) {
    const int l = threadIdx.x & 15;
    const int group0 = (blockIdx.x * blockDim.x + threadIdx.x) >> 4;
    const int ngroups = (gridDim.x * blockDim.x) >> 4;

    const vfloat4 wk0 = *reinterpret_cast<const vfloat4*>(W + 4 * l);
    const vfloat4 wk1 = *reinterpret_cast<const vfloat4*>(W + 64 + 4 * l);
    const vfloat4 wi0 = *reinterpret_cast<const vfloat4*>(W + DIM + 4 * l);
    const vfloat4 wi1 = *reinterpret_cast<const vfloat4*>(W + DIM + 64 + 4 * l);

    // full quads (no bounds checks), then a scalar tail pass
    const int n_full = n_nodes & ~3;

    for (int base = 4 * group0; base < n_full; base += 4 * ngroups) {
        const float* hp = h + (size_t)base * DIM;
        vfloat4 a0[4], a1[4];
#pragma unroll
        for (int j = 0; j < 4; ++j) {
            a0[j] = ntload(hp + (size_t)j * DIM + 4 * l);
            a1[j] = ntload(hp + (size_t)j * DIM + 64 + 4 * l);
        }
        float sk[4], si[4];
#pragma unroll
        for (int j = 0; j < 4; ++j) {
            sk[j] = reduce16(dp4(a0[j], wk0) + dp4(a1[j], wk1));
            si[j] = reduce16(dp4(a0[j], wi0) + dp4(a1[j], wi1));
        }
        if (l == 0) {
            vfloat4 vk; vk.x = sk[0]; vk.y = sk[1]; vk.z = sk[2]; vk.w = sk[3];
            vfloat4 vi; vi.x = si[0]; vi.y = si[1]; vi.z = si[2]; vi.w = si[3];
            *reinterpret_cast<vfloat4*>(pk + base) = vk;  // base%4==0 -> 16B aligned
            *reinterpret_cast<vfloat4*>(pi + base) = vi;
        }
    }
    // tail (< 4 nodes), handled by the first groups
    for (int node = n_full + group0; node < n_nodes; node += ngroups) {
        const float* hp = h + (size_t)node * DIM;
        const vfloat4 a0 = ntload(hp + 4 * l);
        const vfloat4 a1 = ntload(hp + 64 + 4 * l);
        float sk = reduce16(dp4(a0, wk0) + dp4(a1, wk1));
        float si = reduce16(dp4(a0, wi0) + dp4(a1, wi1));
        if (l == 0) { pk[node] = sk; pi[node] = si; }
    }
}

// Kernel 2: per-edge logit = e[edge]·We + pk[src] + pi[dst] + b; out = sigmoid(logit).
// 16 lanes/edge, 4 edges/iter: 8 independent streaming loads + 4 gather chains
// in flight per lane; src/dst read as one int4 each; 16B output store.
__global__ __launch_bounds__(256) void edge_kernel(
        const float* __restrict__ e,
        const int* __restrict__ src,
        const int* __restrict__ dst,
        const float* __restrict__ W,
        const float* __restrict__ b,
        const float* __restrict__ pk,
        const float* __restrict__ pi,
        float* __restrict__ out,
        int n_edges) {
    const int l = threadIdx.x & 15;
    const int group0 = (blockIdx.x * blockDim.x + threadIdx.x) >> 4;
    const int ngroups = (gridDim.x * blockDim.x) >> 4;

    const vfloat4 we0 = *reinterpret_cast<const vfloat4*>(W + 2 * DIM + 4 * l);
    const vfloat4 we1 = *reinterpret_cast<const vfloat4*>(W + 2 * DIM + 64 + 4 * l);
    const float b0 = b[0];

    const int n_full = n_edges & ~3;

    for (int base = 4 * group0; base < n_full; base += 4 * ngroups) {
        // one 16B broadcast load each for 4 edges' indices; gathers issued early
        const vint4 s4 = *reinterpret_cast<const vint4*>(src + base);
        const vint4 d4 = *reinterpret_cast<const vint4*>(dst + base);
        float pkv[4], piv[4];
        pkv[0] = pk[s4.x]; pkv[1] = pk[s4.y]; pkv[2] = pk[s4.z]; pkv[3] = pk[s4.w];
        piv[0] = pi[d4.x]; piv[1] = pi[d4.y]; piv[2] = pi[d4.z]; piv[3] = pi[d4.w];

        const float* ep = e + (size_t)base * DIM;
        vfloat4 a0[4], a1[4];
#pragma unroll
        for (int j = 0; j < 4; ++j) {
            a0[j] = ntload(ep + (size_t)j * DIM + 4 * l);
            a1[j] = ntload(ep + (size_t)j * DIM + 64 + 4 * l);
        }

        float s[4];
#pragma unroll
        for (int j = 0; j < 4; ++j)
            s[j] = reduce16(dp4(a0[j], we0) + dp4(a1[j], we1));

        if (l == 0) {
            vfloat4 o;
            o.x = sigmoidf(s[0] + pkv[0] + piv[0] + b0);
            o.y = sigmoidf(s[1] + pkv[1] + piv[1] + b0);
            o.z = sigmoidf(s[2] + pkv[2] + piv[2] + b0);
            o.w = sigmoidf(s[3] + pkv[3] + piv[3] + b0);
            *reinterpret_cast<vfloat4*>(out + base) = o;  // base%4==0 -> 16B aligned
        }
    }
    // tail (< 4 edges)
    for (int edge = n_full + group0; edge < n_edges; edge += ngroups) {
        const int si_ = src[edge];
        const int di_ = dst[edge];
        const float pkv = pk[si_];
        const float piv = pi[di_];
        const float* ep = e + (size_t)edge * DIM;
        const vfloat4 a0 = ntload(ep + 4 * l);
        const vfloat4 a1 = ntload(ep + 64 + 4 * l);
        float s = reduce16(dp4(a0, we0) + dp4(a1, we1));
        if (l == 0) {
            out[edge] = sigmoidf(s + pkv + piv + b0);
        }
    }
}

// Fallback (only if ws_size is too small): fully fused, gathers h rows per edge.
__global__ void edge_fused_kernel(const float* __restrict__ h,
                                  const float* __restrict__ e,
                                  const int* __restrict__ src,
                                  const int* __restrict__ dst,
                                  const float* __restrict__ W,
                                  const float* __restrict__ b,
                                  float* __restrict__ out,
                                  int n_edges) {
    int tid  = blockIdx.x * blockDim.x + threadIdx.x;
    int edge = tid >> 5;
    int l    = tid & 31;
    if (edge >= n_edges) return;

    int s_idx = src[edge];
    int d_idx = dst[edge];

    const float4 hk = *reinterpret_cast<const float4*>(h + (size_t)s_idx * DIM + 4 * l);
    const float4 hi = *reinterpret_cast<const float4*>(h + (size_t)d_idx * DIM + 4 * l);
    const float4 ev = *reinterpret_cast<const float4*>(e + (size_t)edge * DIM + 4 * l);
    const float4 wk = *reinterpret_cast<const float4*>(W + 4 * l);
    const float4 wi = *reinterpret_cast<const float4*>(W + DIM + 4 * l);
    const float4 we = *reinterpret_cast<const float4*>(W + 2 * DIM + 4 * l);

    float s = hk.x * wk.x + hk.y * wk.y + hk.z * wk.z + hk.w * wk.w
            + hi.x * wi.x + hi.y * wi.y + hi.z * wi.z + hi.w * wi.w
            + ev.x * we.x + ev.y * we.y + ev.z * we.z + ev.w * we.w;
    s += __shfl_xor(s, 1);
    s += __shfl_xor(s, 2);
    s += __shfl_xor(s, 4);
    s += __shfl_xor(s, 8);
    s += __shfl_xor(s, 16);

    if (l == 0) {
        float logit = s + b[0];
        out[edge] = 1.0f / (1.0f + expf(-logit));
    }
}

extern "C" void kernel_launch(void* const* d_in, const int* in_sizes, int n_in,
                              void* d_out, int out_size, void* d_ws, size_t ws_size,
                              hipStream_t stream) {
    const float* h   = (const float*)d_in[0];
    const float* e   = (const float*)d_in[1];
    const int*   src = (const int*)d_in[2];
    const int*   dst = (const int*)d_in[3];
    const float* W   = (const float*)d_in[4];
    const float* b   = (const float*)d_in[5];
    float* out = (float*)d_out;

    const int n_nodes = in_sizes[0] / DIM;
    const int n_edges = in_sizes[2];

    const size_t ws_needed = 2 * (size_t)n_nodes * sizeof(float);

    if (ws_size >= ws_needed) {
        float* pk = (float*)d_ws;
        float* pi = pk + n_nodes;

        {
            const int block = 256;
            // 16 lanes per node, 4 nodes per group-iteration
            long total = ((long)n_nodes + 3) / 4 * 16;
            int grid = (int)((total + block - 1) / block);
            if (grid > 2048) grid = 2048;
            node_proj_kernel<<<grid, block, 0, stream>>>(h, W, pk, pi, n_nodes);
        }
        {
            const int block = 256;
            long total = ((long)n_edges + 3) / 4 * 16;
            int grid = (int)((total + block - 1) / block);
            if (grid > 2048) grid = 2048;
            edge_kernel<<<grid, block, 0, stream>>>(e, src, dst, W, b, pk, pi, out, n_edges);
        }
    } else {
        int total = n_edges * 32;
        int block = 256;
        int grid  = (total + block - 1) / block;
        edge_fused_kernel<<<grid, block, 0, stream>>>(h, e, src, dst, W, b, out, n_edges);
    }
}